// Round 15
// baseline (391.018 us; speedup 1.0000x reference)
//
#include <hip/hip_runtime.h>

typedef unsigned short ushort_t;
using frag_ab = __attribute__((ext_vector_type(8))) short;
using f32x4   = __attribute__((ext_vector_type(4))) float;
using u32x4   = __attribute__((ext_vector_type(4))) unsigned int;
using u32x2   = __attribute__((ext_vector_type(2))) unsigned int;

#define FDIM 512
#define NH 8
#define FATT 64
#define NX 2048
#define NP 4096
#define NTOT 6144

__device__ __forceinline__ ushort_t f2bf(float f) {
    unsigned u = __float_as_uint(f);
    u = (u + 0x7FFFu + ((u >> 16) & 1u)) >> 16;   // RTNE
    return (ushort_t)u;
}
__device__ __forceinline__ float bf2f(ushort_t s) {
    return __uint_as_float(((unsigned)s) << 16);
}
__device__ __forceinline__ unsigned pk2bf(float a, float b) {
    return (unsigned)f2bf(a) | ((unsigned)f2bf(b) << 16);
}

// ---------------------------------------------------------------------------
// K0: fp32 -> bf16 conversions: f = concat(fx, fp0), Wembd, Wfc, Wout
// ---------------------------------------------------------------------------
__global__ __launch_bounds__(256) void k_prep(const float* __restrict__ fx,
                                              const float* __restrict__ fp,
                                              const float* __restrict__ We,
                                              const float* __restrict__ Wfc,
                                              const float* __restrict__ Wout,
                                              ushort_t* __restrict__ f_b,
                                              ushort_t* __restrict__ We_b,
                                              ushort_t* __restrict__ Wfc_b,
                                              ushort_t* __restrict__ Wout_b) {
    int i = blockIdx.x * 256 + threadIdx.x;
    int stride = gridDim.x * 256;
    const int NF4 = NTOT * FDIM / 4;
    const int NX4 = NX * FDIM / 4;
    for (int idx = i; idx < NF4; idx += stride) {
        float4 v = (idx < NX4) ? ((const float4*)fx)[idx]
                               : ((const float4*)fp)[idx - NX4];
        ushort4 o;
        o.x = f2bf(v.x); o.y = f2bf(v.y); o.z = f2bf(v.z); o.w = f2bf(v.w);
        ((ushort4*)f_b)[idx] = o;
    }
    const int NW4 = FDIM * FDIM / 4;
    for (int idx = i; idx < NW4; idx += stride) {
        float4 v = ((const float4*)We)[idx];
        ushort4 o;
        o.x = f2bf(v.x); o.y = f2bf(v.y); o.z = f2bf(v.z); o.w = f2bf(v.w);
        ((ushort4*)We_b)[idx] = o;
    }
    const int NFC4 = NH * FATT * 2 * FATT / 4;
    for (int idx = i; idx < NFC4; idx += stride) {
        float4 v = ((const float4*)Wfc)[idx];
        ushort4 o;
        o.x = f2bf(v.x); o.y = f2bf(v.y); o.z = f2bf(v.z); o.w = f2bf(v.w);
        ((ushort4*)Wfc_b)[idx] = o;
    }
    for (int idx = i; idx < NW4; idx += stride) {
        float4 v = ((const float4*)Wout)[idx];
        ushort4 o;
        o.x = f2bf(v.x); o.y = f2bf(v.y); o.z = f2bf(v.z); o.w = f2bf(v.w);
        ((ushort4*)Wout_b)[idx] = o;
    }
}

// ---------------------------------------------------------------------------
// K1: femb[h][n][e] = f[n] . Wembd[h][e] + bembd  (MFMA GEMM, bf16 out)
//     also writes fpT[h][e][p] (n>=NX) and facat[h][x][64+e] (n<NX)
// ---------------------------------------------------------------------------
__global__ __launch_bounds__(256) void k_embed(const ushort_t* __restrict__ f_b,
                                               const ushort_t* __restrict__ We_b,
                                               const float* __restrict__ bembd,
                                               ushort_t* __restrict__ femb_b,
                                               ushort_t* __restrict__ fpT_b,
                                               ushort_t* __restrict__ facat_b) {
    int tid = threadIdx.x;
    int wv = tid >> 6, lane = tid & 63;
    int g = lane >> 4, c = lane & 15;
    int m0 = blockIdx.x * 64 + wv * 16;
    int o0 = blockIdx.y * 64;

    f32x4 acc[4] = {};
    const ushort_t* arow = f_b + (size_t)(m0 + c) * FDIM + g * 8;
#pragma unroll 4
    for (int ks = 0; ks < FDIM; ks += 32) {
        frag_ab a = *(const frag_ab*)(arow + ks);
#pragma unroll
        for (int t = 0; t < 4; ++t) {
            const ushort_t* brow = We_b + (size_t)(o0 + t * 16 + c) * FDIM + ks + g * 8;
            frag_ab b = *(const frag_ab*)brow;
            acc[t] = __builtin_amdgcn_mfma_f32_16x16x32_bf16(a, b, acc[t], 0, 0, 0);
        }
    }
#pragma unroll
    for (int t = 0; t < 4; ++t) {
        int o = o0 + t * 16 + c;           // output feature = h*64+e
        int h = o >> 6, e = o & 63;
        float bia = bembd[o];
#pragma unroll
        for (int r = 0; r < 4; ++r) {
            int n = m0 + g * 4 + r;
            ushort_t v = f2bf(acc[t][r] + bia);
            femb_b[((size_t)h * NTOT + n) * FATT + e] = v;
            if (n >= NX) fpT_b[((size_t)h * FATT + e) * NP + (n - NX)] = v;
            else         facat_b[((size_t)h * NX + n) * 128 + 64 + e] = v;
        }
    }
}

// ---------------------------------------------------------------------------
// K2: FUSED attention, BPERMUTE-FREE pass 1. The swapped-QK D-layout (lane
//   (g,c) holds P[p=ps+4g+r][x=c]) feeds a zero-padded K=32 MFMA directly:
//   B nonzero k-slots 8g..8g+3 carry P[ps+4g+j][c]; A low half carries
//   fpT[t2*16+c][ps+4g+j], high half zero. No cross-lane ops in the loop.
//   Pass 2 unchanged (recompute + NT stores).
// ---------------------------------------------------------------------------
__global__ __launch_bounds__(512) void k_attn_f(const ushort_t* __restrict__ femb_b,
                                                const ushort_t* __restrict__ fpT_b,
                                                float* __restrict__ w_out,
                                                ushort_t* __restrict__ facat_b) {
    int bid = blockIdx.x;
    int h  = bid & 7;                 // XCD affinity
    int xt = bid >> 3;                // 0..127
    int tid = threadIdx.x;
    int wv = tid >> 6;                // 0..7 -> p slice
    int lane = tid & 63;
    int g = lane >> 4, c = lane & 15;

    __shared__ float lds_pv[8][16][68];   // padded stride 68 (bank spread)
    __shared__ float lds_sum[8][16];
    __shared__ float lds_inv[16];

    const ushort_t* fxb = femb_b + (size_t)h * NTOT * FATT;
    const ushort_t* fpb = fxb + (size_t)NX * FATT;
    const ushort_t* fTb = fpT_b + (size_t)h * FATT * NP;

    // QK B-operand: fx cols (x = xt*16 + c), k = e
    const ushort_t* brow = fxb + (size_t)(xt * 16 + c) * FATT + g * 8;
    frag_ab bx0 = *(const frag_ab*)(brow);
    frag_ab bx1 = *(const frag_ab*)(brow + 32);

    f32x4 pacc[4] = {};
    float rsum = 0.f;                 // per-lane partial for x = c

    const int p0 = wv * 512;
    // ---- pass 1: 16-p steps, no cross-lane relay ----
    for (int ps = p0; ps < p0 + 512; ps += 16) {
        // swapped QK: A = fp rows (p = ps+c), k = e
        const ushort_t* arow = fpb + (size_t)(ps + c) * FATT + g * 8;
        f32x4 s = {};
        s = __builtin_amdgcn_mfma_f32_16x16x32_bf16(*(const frag_ab*)arow, bx0, s, 0, 0, 0);
        s = __builtin_amdgcn_mfma_f32_16x16x32_bf16(*(const frag_ab*)(arow + 32), bx1, s, 0, 0, 0);
        // lane (g,c): S[p=ps+4g+r][x=c]
        float e0 = __expf(s[0] * 0.125f);
        float e1 = __expf(s[1] * 0.125f);
        float e2 = __expf(s[2] * 0.125f);
        float e3 = __expf(s[3] * 0.125f);
        rsum += (e0 + e1) + (e2 + e3);
        // PV B-operand: zero-padded K=32 frag, nonzero k=8g..8g+3 = P[ps+4g+j][c]
        u32x4 bw;
        bw[0] = pk2bf(e0, e1);
        bw[1] = pk2bf(e2, e3);
        bw[2] = 0u;
        bw[3] = 0u;
        frag_ab pb = __builtin_bit_cast(frag_ab, bw);
#pragma unroll
        for (int t2 = 0; t2 < 4; ++t2) {
            // A: V^T rows (e = t2*16+c), k-slots 8g..8g+3 = fpT[e][ps+4g+j]
            const ushort_t* vrow = fTb + (size_t)(t2 * 16 + c) * NP + ps + g * 4;
            u32x2 vl = *(const u32x2*)vrow;
            u32x4 aw;
            aw[0] = vl[0];
            aw[1] = vl[1];
            aw[2] = 0u;
            aw[3] = 0u;
            frag_ab va = __builtin_bit_cast(frag_ab, aw);
            // D[e'][x]: lane (g,c) accumulates PV[e=t2*16+4g+r][x=c]
            pacc[t2] = __builtin_amdgcn_mfma_f32_16x16x32_bf16(va, pb, pacc[t2], 0, 0, 0);
        }
    }

    // in-wave row-sum over g; all lanes end with slice total for x=c
    rsum += __shfl_xor(rsum, 16);
    rsum += __shfl_xor(rsum, 32);
    if (lane < 16) lds_sum[wv][c] = rsum;
    // PV partials: pacc[t2][r] = PV[e=t2*16+4g+r][x=c] -> lds_pv[wv][x][e]
#pragma unroll
    for (int t2 = 0; t2 < 4; ++t2)
        *(f32x4*)&lds_pv[wv][c][t2 * 16 + 4 * g] = pacc[t2];
    __syncthreads();

    // cross-wave combine: 1024 values over 512 threads (2 each)
#pragma unroll
    for (int k = 0; k < 2; ++k) {
        int v = tid + k * 512;
        int row = v >> 6, e = v & 63;
        float stot = 0.f, val = 0.f;
#pragma unroll
        for (int w = 0; w < 8; ++w) {
            stot += lds_sum[w][row];
            val  += lds_pv[w][row][e];
        }
        facat_b[((size_t)h * NX + xt * 16 + row) * 128 + e] = f2bf(val / stot);
    }
    if (tid < 16) {
        float stot = 0.f;
#pragma unroll
        for (int w = 0; w < 8; ++w) stot += lds_sum[w][tid];
        lds_inv[tid] = 1.f / stot;
    }
    __syncthreads();

    // ---- pass 2: recompute QK for my slice, write normalized w (NT) ----
    float inv_c = lds_inv[c];                     // for x = c
    float* wrow = w_out + ((size_t)(xt * 16 + c) * NH + h) * NP;
    for (int ps = p0; ps < p0 + 512; ps += 16) {
        const ushort_t* arow = fpb + (size_t)(ps + c) * FATT + g * 8;
        f32x4 s = {};
        s = __builtin_amdgcn_mfma_f32_16x16x32_bf16(*(const frag_ab*)arow, bx0, s, 0, 0, 0);
        s = __builtin_amdgcn_mfma_f32_16x16x32_bf16(*(const frag_ab*)(arow + 32), bx1, s, 0, 0, 0);
        f32x4 o;
        o[0] = __expf(s[0] * 0.125f) * inv_c;
        o[1] = __expf(s[1] * 0.125f) * inv_c;
        o[2] = __expf(s[2] * 0.125f) * inv_c;
        o[3] = __expf(s[3] * 0.125f) * inv_c;
        __builtin_nontemporal_store(o, (f32x4*)(wrow + ps + g * 4));
    }
}

// ---------------------------------------------------------------------------
// K2p: d_out write-speed probe — identity RMW over the 268MB w region.
//   scale is 1.0f at runtime (bit-exact: w values are normal positives).
//   Probe dur = Delta(total) attributes d_out store bandwidth decisively.
// ---------------------------------------------------------------------------
__global__ __launch_bounds__(256) void k_probe(float* __restrict__ w, float scale) {
    const size_t N4 = (size_t)NX * NH * NP / 4;
    size_t i = (size_t)blockIdx.x * 256 + threadIdx.x;
    size_t stride = (size_t)gridDim.x * 256;
    for (size_t idx = i; idx < N4; idx += stride) {
        f32x4 v = ((const f32x4*)w)[idx];
        v *= scale;
        __builtin_nontemporal_store(v, ((f32x4*)w) + idx);
    }
}

// ---------------------------------------------------------------------------
// K3: fc — per-head MFMA GEMM (2048 x 64out x 128k), relu, bf16 out
// ---------------------------------------------------------------------------
__global__ __launch_bounds__(256) void k_fc(const ushort_t* __restrict__ facat_b,
                                            const ushort_t* __restrict__ Wfc_b,
                                            const float* __restrict__ bfc,
                                            ushort_t* __restrict__ fcout_b) {
    int tid = threadIdx.x;
    int wv = tid >> 6, lane = tid & 63;
    int g = lane >> 4, c = lane & 15;
    int x0 = blockIdx.x * 64 + wv * 16;
    int h = blockIdx.y;

    const ushort_t* A = facat_b + ((size_t)h * NX + x0 + c) * 128 + g * 8;
    const ushort_t* B = Wfc_b + (size_t)h * FATT * 128;

    f32x4 acc[4] = {};
#pragma unroll
    for (int ks = 0; ks < 128; ks += 32) {
        frag_ab a = *(const frag_ab*)(A + ks);
#pragma unroll
        for (int t = 0; t < 4; ++t) {
            frag_ab b = *(const frag_ab*)(B + (size_t)(t * 16 + c) * 128 + ks + g * 8);
            acc[t] = __builtin_amdgcn_mfma_f32_16x16x32_bf16(a, b, acc[t], 0, 0, 0);
        }
    }
#pragma unroll
    for (int t = 0; t < 4; ++t) {
        int e = t * 16 + c;
        float bia = bfc[h * FATT + e];
#pragma unroll
        for (int r = 0; r < 4; ++r) {
            int x = x0 + g * 4 + r;
            fcout_b[(size_t)x * FDIM + h * FATT + e] = f2bf(fmaxf(acc[t][r] + bia, 0.f));
        }
    }
}

// ---------------------------------------------------------------------------
// K4: out GEMM (2048 x 512 x 512) MFMA + residual + bias + relu (fp32 out)
// ---------------------------------------------------------------------------
__global__ __launch_bounds__(256) void k_out(const float* __restrict__ fx_in,
                                             const ushort_t* __restrict__ fcout_b,
                                             const ushort_t* __restrict__ Wout_b,
                                             const float* __restrict__ bout,
                                             float* __restrict__ out) {
    int tid = threadIdx.x;
    int wv = tid >> 6, lane = tid & 63;
    int g = lane >> 4, c = lane & 15;
    int x0 = blockIdx.x * 64 + wv * 16;
    int o0 = blockIdx.y * 64;

    f32x4 acc[4] = {};
    const ushort_t* A = fcout_b + (size_t)(x0 + c) * FDIM + g * 8;
#pragma unroll 4
    for (int ks = 0; ks < FDIM; ks += 32) {
        frag_ab a = *(const frag_ab*)(A + ks);
#pragma unroll
        for (int t = 0; t < 4; ++t) {
            frag_ab b = *(const frag_ab*)(Wout_b + (size_t)(o0 + t * 16 + c) * FDIM + ks + g * 8);
            acc[t] = __builtin_amdgcn_mfma_f32_16x16x32_bf16(a, b, acc[t], 0, 0, 0);
        }
    }
#pragma unroll
    for (int t = 0; t < 4; ++t) {
        int f = o0 + t * 16 + c;
        float bia = bout[f];
#pragma unroll
        for (int r = 0; r < 4; ++r) {
            int x = x0 + g * 4 + r;
            float v = acc[t][r] + bia + fx_in[(size_t)x * FDIM + f];
            out[(size_t)x * FDIM + f] = fmaxf(v, 0.f);
        }
    }
}

extern "C" void kernel_launch(void* const* d_in, const int* in_sizes, int n_in,
                              void* d_out, int out_size, void* d_ws, size_t ws_size,
                              hipStream_t stream) {
    const float* fx_in = (const float*)d_in[0];
    const float* fp_in = (const float*)d_in[1];
    const float* Wembd = (const float*)d_in[2];
    const float* bembd = (const float*)d_in[3];
    const float* Wfc   = (const float*)d_in[4];
    const float* bfc   = (const float*)d_in[5];
    const float* Wout  = (const float*)d_in[6];
    const float* bout  = (const float*)d_in[7];

    float* out   = (float*)d_out;
    float* w_out = out + (size_t)NX * FDIM;

    ushort_t* f_b     = (ushort_t*)d_ws;                     // 6144*512
    ushort_t* We_b    = f_b + (size_t)NTOT * FDIM;           // 512*512
    ushort_t* femb_b  = We_b + (size_t)FDIM * FDIM;          // 8*6144*64
    ushort_t* fpT_b   = femb_b + (size_t)NH * NTOT * FATT;   // 8*64*4096
    ushort_t* facat_b = fpT_b + (size_t)NH * FATT * NP;      // 8*2048*128
    ushort_t* fcout_b = facat_b + (size_t)NH * NX * 128;     // 2048*512
    ushort_t* Wfc_b   = fcout_b + (size_t)NX * FDIM;         // 8*64*128
    ushort_t* Wout_b  = Wfc_b + (size_t)NH * FATT * 2 * FATT;// 512*512

    k_prep  <<<1024, 256, 0, stream>>>(fx_in, fp_in, Wembd, Wfc, Wout,
                                       f_b, We_b, Wfc_b, Wout_b);
    k_embed <<<dim3(96, 8), 256, 0, stream>>>(f_b, We_b, bembd, femb_b, fpT_b, facat_b);
    k_attn_f<<<1024, 512, 0, stream>>>(femb_b, fpT_b, w_out, facat_b);
    k_probe <<<4096, 256, 0, stream>>>(w_out, 1.0f);
    k_fc    <<<dim3(32, 8), 256, 0, stream>>>(facat_b, Wfc_b, bfc, fcout_b);
    k_out   <<<dim3(32, 8), 256, 0, stream>>>(fx_in, fcout_b, Wout_b, bout, out);
}

// Round 16
// 227.091 us; speedup vs baseline: 1.7219x; 1.7219x over previous
//
#include <hip/hip_runtime.h>

typedef unsigned short ushort_t;
using frag_ab = __attribute__((ext_vector_type(8))) short;
using f32x4   = __attribute__((ext_vector_type(4))) float;
using u32x4   = __attribute__((ext_vector_type(4))) unsigned int;
using u32x2   = __attribute__((ext_vector_type(2))) unsigned int;

#define FDIM 512
#define NH 8
#define FATT 64
#define NX 2048
#define NP 4096
#define NTOT 6144

__device__ __forceinline__ ushort_t f2bf(float f) {
    unsigned u = __float_as_uint(f);
    u = (u + 0x7FFFu + ((u >> 16) & 1u)) >> 16;   // RTNE
    return (ushort_t)u;
}
__device__ __forceinline__ float bf2f(ushort_t s) {
    return __uint_as_float(((unsigned)s) << 16);
}
__device__ __forceinline__ unsigned pk2bf(float a, float b) {
    return (unsigned)f2bf(a) | ((unsigned)f2bf(b) << 16);
}

// ---------------------------------------------------------------------------
// K0: fp32 -> bf16 conversions: f = concat(fx, fp0), Wembd, Wfc, Wout
// ---------------------------------------------------------------------------
__global__ __launch_bounds__(256) void k_prep(const float* __restrict__ fx,
                                              const float* __restrict__ fp,
                                              const float* __restrict__ We,
                                              const float* __restrict__ Wfc,
                                              const float* __restrict__ Wout,
                                              ushort_t* __restrict__ f_b,
                                              ushort_t* __restrict__ We_b,
                                              ushort_t* __restrict__ Wfc_b,
                                              ushort_t* __restrict__ Wout_b) {
    int i = blockIdx.x * 256 + threadIdx.x;
    int stride = gridDim.x * 256;
    const int NF4 = NTOT * FDIM / 4;
    const int NX4 = NX * FDIM / 4;
    for (int idx = i; idx < NF4; idx += stride) {
        float4 v = (idx < NX4) ? ((const float4*)fx)[idx]
                               : ((const float4*)fp)[idx - NX4];
        ushort4 o;
        o.x = f2bf(v.x); o.y = f2bf(v.y); o.z = f2bf(v.z); o.w = f2bf(v.w);
        ((ushort4*)f_b)[idx] = o;
    }
    const int NW4 = FDIM * FDIM / 4;
    for (int idx = i; idx < NW4; idx += stride) {
        float4 v = ((const float4*)We)[idx];
        ushort4 o;
        o.x = f2bf(v.x); o.y = f2bf(v.y); o.z = f2bf(v.z); o.w = f2bf(v.w);
        ((ushort4*)We_b)[idx] = o;
    }
    const int NFC4 = NH * FATT * 2 * FATT / 4;
    for (int idx = i; idx < NFC4; idx += stride) {
        float4 v = ((const float4*)Wfc)[idx];
        ushort4 o;
        o.x = f2bf(v.x); o.y = f2bf(v.y); o.z = f2bf(v.z); o.w = f2bf(v.w);
        ((ushort4*)Wfc_b)[idx] = o;
    }
    for (int idx = i; idx < NW4; idx += stride) {
        float4 v = ((const float4*)Wout)[idx];
        ushort4 o;
        o.x = f2bf(v.x); o.y = f2bf(v.y); o.z = f2bf(v.z); o.w = f2bf(v.w);
        ((ushort4*)Wout_b)[idx] = o;
    }
}

// ---------------------------------------------------------------------------
// K1: femb[h][n][e] = f[n] . Wembd[h][e] + bembd  (MFMA GEMM, bf16 out)
//     also writes fpT[h][e][p] (n>=NX) and facat[h][x][64+e] (n<NX)
// ---------------------------------------------------------------------------
__global__ __launch_bounds__(256) void k_embed(const ushort_t* __restrict__ f_b,
                                               const ushort_t* __restrict__ We_b,
                                               const float* __restrict__ bembd,
                                               ushort_t* __restrict__ femb_b,
                                               ushort_t* __restrict__ fpT_b,
                                               ushort_t* __restrict__ facat_b) {
    int tid = threadIdx.x;
    int wv = tid >> 6, lane = tid & 63;
    int g = lane >> 4, c = lane & 15;
    int m0 = blockIdx.x * 64 + wv * 16;
    int o0 = blockIdx.y * 64;

    f32x4 acc[4] = {};
    const ushort_t* arow = f_b + (size_t)(m0 + c) * FDIM + g * 8;
#pragma unroll 4
    for (int ks = 0; ks < FDIM; ks += 32) {
        frag_ab a = *(const frag_ab*)(arow + ks);
#pragma unroll
        for (int t = 0; t < 4; ++t) {
            const ushort_t* brow = We_b + (size_t)(o0 + t * 16 + c) * FDIM + ks + g * 8;
            frag_ab b = *(const frag_ab*)brow;
            acc[t] = __builtin_amdgcn_mfma_f32_16x16x32_bf16(a, b, acc[t], 0, 0, 0);
        }
    }
#pragma unroll
    for (int t = 0; t < 4; ++t) {
        int o = o0 + t * 16 + c;           // output feature = h*64+e
        int h = o >> 6, e = o & 63;
        float bia = bembd[o];
#pragma unroll
        for (int r = 0; r < 4; ++r) {
            int n = m0 + g * 4 + r;
            ushort_t v = f2bf(acc[t][r] + bia);
            femb_b[((size_t)h * NTOT + n) * FATT + e] = v;
            if (n >= NX) fpT_b[((size_t)h * FATT + e) * NP + (n - NX)] = v;
            else         facat_b[((size_t)h * NX + n) * 128 + 64 + e] = v;
        }
    }
}

// ---------------------------------------------------------------------------
// K2: attention v2 — TRAFFIC-MINIMAL: 256 blocks (1/CU), 64 x-rows per block.
//   Each wave holds Q-frags for 4 x-groups in registers and amortizes every
//   K-row / V-row read over 64 x. Zero-pad PV (validated round 15), swapped
//   QK (validated round 7+), NT stores. Cross-wave combine: 8-round LDS acc.
//   Per-CU traffic ~2.6MB vs old ~6MB (the ~10 B/cyc/CU pipe law).
// ---------------------------------------------------------------------------
__global__ __launch_bounds__(512) void k_attn2(const ushort_t* __restrict__ femb_b,
                                               const ushort_t* __restrict__ fpT_b,
                                               float* __restrict__ w_out,
                                               ushort_t* __restrict__ facat_b) {
    int bid = blockIdx.x;
    int h  = bid & 7;                 // head == XCD affinity
    int xb = bid >> 3;                // 0..31, x-base = xb*64
    int tid = threadIdx.x;
    int wv = tid >> 6;                // 0..7 -> 512-p slice
    int lane = tid & 63;
    int g = lane >> 4, c = lane & 15;

    __shared__ float lds_pv[64][68];  // combined PV [x_local][e], pad 68
    __shared__ float lds_sum[64];
    __shared__ float lds_inv[64];

    const ushort_t* fxb = femb_b + (size_t)h * NTOT * FATT;
    const ushort_t* fpb = fxb + (size_t)NX * FATT;
    const ushort_t* fTb = fpT_b + (size_t)h * FATT * NP;

    // Q B-frags for 4 x-groups (held in registers for both passes)
    frag_ab bx0_0, bx0_1, bx1_0, bx1_1, bx2_0, bx2_1, bx3_0, bx3_1;
    {
        const ushort_t* b0 = fxb + (size_t)(xb * 64 + 0 * 16 + c) * FATT + g * 8;
        const ushort_t* b1 = fxb + (size_t)(xb * 64 + 1 * 16 + c) * FATT + g * 8;
        const ushort_t* b2 = fxb + (size_t)(xb * 64 + 2 * 16 + c) * FATT + g * 8;
        const ushort_t* b3 = fxb + (size_t)(xb * 64 + 3 * 16 + c) * FATT + g * 8;
        bx0_0 = *(const frag_ab*)b0;  bx0_1 = *(const frag_ab*)(b0 + 32);
        bx1_0 = *(const frag_ab*)b1;  bx1_1 = *(const frag_ab*)(b1 + 32);
        bx2_0 = *(const frag_ab*)b2;  bx2_1 = *(const frag_ab*)(b2 + 32);
        bx3_0 = *(const frag_ab*)b3;  bx3_1 = *(const frag_ab*)(b3 + 32);
    }

    f32x4 pacc[4][4] = {};            // [xg][t2], static indices only
    float rsum[4] = {0.f, 0.f, 0.f, 0.f};
    const int p0 = wv * 512;

    // ---- pass 1: QK + exp + rsum + PV, one K/V read serves 64 x ----
    for (int ps = p0; ps < p0 + 512; ps += 16) {
        const ushort_t* ar = fpb + (size_t)(ps + c) * FATT + g * 8;
        frag_ab a0 = *(const frag_ab*)ar;
        frag_ab a1 = *(const frag_ab*)(ar + 32);
        frag_ab pb[4];
#pragma unroll
        for (int xg = 0; xg < 4; ++xg) {
            frag_ab q0 = (xg == 0) ? bx0_0 : (xg == 1) ? bx1_0 : (xg == 2) ? bx2_0 : bx3_0;
            frag_ab q1 = (xg == 0) ? bx0_1 : (xg == 1) ? bx1_1 : (xg == 2) ? bx2_1 : bx3_1;
            f32x4 s = {};
            s = __builtin_amdgcn_mfma_f32_16x16x32_bf16(a0, q0, s, 0, 0, 0);
            s = __builtin_amdgcn_mfma_f32_16x16x32_bf16(a1, q1, s, 0, 0, 0);
            float e0 = __expf(s[0] * 0.125f);
            float e1 = __expf(s[1] * 0.125f);
            float e2 = __expf(s[2] * 0.125f);
            float e3 = __expf(s[3] * 0.125f);
            rsum[xg] += (e0 + e1) + (e2 + e3);
            u32x4 bw;
            bw[0] = pk2bf(e0, e1);
            bw[1] = pk2bf(e2, e3);
            bw[2] = 0u;
            bw[3] = 0u;
            pb[xg] = __builtin_bit_cast(frag_ab, bw);
        }
#pragma unroll
        for (int t2 = 0; t2 < 4; ++t2) {
            const ushort_t* vr = fTb + (size_t)(t2 * 16 + c) * NP + ps + g * 4;
            u32x2 vl = *(const u32x2*)vr;
            u32x4 aw;
            aw[0] = vl[0];
            aw[1] = vl[1];
            aw[2] = 0u;
            aw[3] = 0u;
            frag_ab va = __builtin_bit_cast(frag_ab, aw);
#pragma unroll
            for (int xg = 0; xg < 4; ++xg)
                pacc[xg][t2] = __builtin_amdgcn_mfma_f32_16x16x32_bf16(va, pb[xg], pacc[xg][t2], 0, 0, 0);
        }
    }

    // reduce rsum over g (lane bits 4,5)
#pragma unroll
    for (int xg = 0; xg < 4; ++xg) {
        rsum[xg] += __shfl_xor(rsum[xg], 16);
        rsum[xg] += __shfl_xor(rsum[xg], 32);
    }

    // ---- cross-wave combine: 8 serialized accumulation rounds ----
    for (int w = 0; w < 8; ++w) {
        if (wv == w) {
            if (w == 0) {
                if (lane < 16) {
#pragma unroll
                    for (int xg = 0; xg < 4; ++xg) lds_sum[xg * 16 + c] = rsum[xg];
                }
#pragma unroll
                for (int xg = 0; xg < 4; ++xg)
#pragma unroll
                    for (int t2 = 0; t2 < 4; ++t2)
                        *(f32x4*)&lds_pv[xg * 16 + c][t2 * 16 + 4 * g] = pacc[xg][t2];
            } else {
                if (lane < 16) {
#pragma unroll
                    for (int xg = 0; xg < 4; ++xg) lds_sum[xg * 16 + c] += rsum[xg];
                }
#pragma unroll
                for (int xg = 0; xg < 4; ++xg)
#pragma unroll
                    for (int t2 = 0; t2 < 4; ++t2) {
                        f32x4 cur = *(const f32x4*)&lds_pv[xg * 16 + c][t2 * 16 + 4 * g];
                        cur += pacc[xg][t2];
                        *(f32x4*)&lds_pv[xg * 16 + c][t2 * 16 + 4 * g] = cur;
                    }
            }
        }
        __syncthreads();
    }
    if (tid < 64) lds_inv[tid] = 1.f / lds_sum[tid];
    __syncthreads();

    // ---- facat write: 512 threads x 8 elems = 64 x-rows x 64 e ----
    {
        int row = tid >> 3;
        int e0 = (tid & 7) * 8;
        float inv = lds_inv[row];
        u32x4 o;
#pragma unroll
        for (int j = 0; j < 4; ++j)
            o[j] = pk2bf(lds_pv[row][e0 + 2 * j] * inv, lds_pv[row][e0 + 2 * j + 1] * inv);
        *(u32x4*)&facat_b[((size_t)h * NX + xb * 64 + row) * 128 + e0] = o;
    }

    // ---- pass 2: recompute QK, write normalized w (NT), 64 x per A-read ----
    float invc0 = lds_inv[0 * 16 + c];
    float invc1 = lds_inv[1 * 16 + c];
    float invc2 = lds_inv[2 * 16 + c];
    float invc3 = lds_inv[3 * 16 + c];
    for (int ps = p0; ps < p0 + 512; ps += 16) {
        const ushort_t* ar = fpb + (size_t)(ps + c) * FATT + g * 8;
        frag_ab a0 = *(const frag_ab*)ar;
        frag_ab a1 = *(const frag_ab*)(ar + 32);
#pragma unroll
        for (int xg = 0; xg < 4; ++xg) {
            frag_ab q0 = (xg == 0) ? bx0_0 : (xg == 1) ? bx1_0 : (xg == 2) ? bx2_0 : bx3_0;
            frag_ab q1 = (xg == 0) ? bx0_1 : (xg == 1) ? bx1_1 : (xg == 2) ? bx2_1 : bx3_1;
            float invc = (xg == 0) ? invc0 : (xg == 1) ? invc1 : (xg == 2) ? invc2 : invc3;
            f32x4 s = {};
            s = __builtin_amdgcn_mfma_f32_16x16x32_bf16(a0, q0, s, 0, 0, 0);
            s = __builtin_amdgcn_mfma_f32_16x16x32_bf16(a1, q1, s, 0, 0, 0);
            f32x4 o;
            o[0] = __expf(s[0] * 0.125f) * invc;
            o[1] = __expf(s[1] * 0.125f) * invc;
            o[2] = __expf(s[2] * 0.125f) * invc;
            o[3] = __expf(s[3] * 0.125f) * invc;
            float* dst = w_out + ((size_t)(xb * 64 + xg * 16 + c) * NH + h) * NP + ps + g * 4;
            __builtin_nontemporal_store(o, (f32x4*)dst);
        }
    }
}

// ---------------------------------------------------------------------------
// K3: fc — per-head MFMA GEMM (2048 x 64out x 128k), relu, bf16 out
// ---------------------------------------------------------------------------
__global__ __launch_bounds__(256) void k_fc(const ushort_t* __restrict__ facat_b,
                                            const ushort_t* __restrict__ Wfc_b,
                                            const float* __restrict__ bfc,
                                            ushort_t* __restrict__ fcout_b) {
    int tid = threadIdx.x;
    int wv = tid >> 6, lane = tid & 63;
    int g = lane >> 4, c = lane & 15;
    int x0 = blockIdx.x * 64 + wv * 16;
    int h = blockIdx.y;

    const ushort_t* A = facat_b + ((size_t)h * NX + x0 + c) * 128 + g * 8;
    const ushort_t* B = Wfc_b + (size_t)h * FATT * 128;

    f32x4 acc[4] = {};
#pragma unroll
    for (int ks = 0; ks < 128; ks += 32) {
        frag_ab a = *(const frag_ab*)(A + ks);
#pragma unroll
        for (int t = 0; t < 4; ++t) {
            frag_ab b = *(const frag_ab*)(B + (size_t)(t * 16 + c) * 128 + ks + g * 8);
            acc[t] = __builtin_amdgcn_mfma_f32_16x16x32_bf16(a, b, acc[t], 0, 0, 0);
        }
    }
#pragma unroll
    for (int t = 0; t < 4; ++t) {
        int e = t * 16 + c;
        float bia = bfc[h * FATT + e];
#pragma unroll
        for (int r = 0; r < 4; ++r) {
            int x = x0 + g * 4 + r;
            fcout_b[(size_t)x * FDIM + h * FATT + e] = f2bf(fmaxf(acc[t][r] + bia, 0.f));
        }
    }
}

// ---------------------------------------------------------------------------
// K4: out GEMM (2048 x 512 x 512) MFMA + residual + bias + relu (fp32 out)
// ---------------------------------------------------------------------------
__global__ __launch_bounds__(256) void k_out(const float* __restrict__ fx_in,
                                             const ushort_t* __restrict__ fcout_b,
                                             const ushort_t* __restrict__ Wout_b,
                                             const float* __restrict__ bout,
                                             float* __restrict__ out) {
    int tid = threadIdx.x;
    int wv = tid >> 6, lane = tid & 63;
    int g = lane >> 4, c = lane & 15;
    int x0 = blockIdx.x * 64 + wv * 16;
    int o0 = blockIdx.y * 64;

    f32x4 acc[4] = {};
    const ushort_t* A = fcout_b + (size_t)(x0 + c) * FDIM + g * 8;
#pragma unroll 4
    for (int ks = 0; ks < FDIM; ks += 32) {
        frag_ab a = *(const frag_ab*)(A + ks);
#pragma unroll
        for (int t = 0; t < 4; ++t) {
            frag_ab b = *(const frag_ab*)(Wout_b + (size_t)(o0 + t * 16 + c) * FDIM + ks + g * 8);
            acc[t] = __builtin_amdgcn_mfma_f32_16x16x32_bf16(a, b, acc[t], 0, 0, 0);
        }
    }
#pragma unroll
    for (int t = 0; t < 4; ++t) {
        int f = o0 + t * 16 + c;
        float bia = bout[f];
#pragma unroll
        for (int r = 0; r < 4; ++r) {
            int x = x0 + g * 4 + r;
            float v = acc[t][r] + bia + fx_in[(size_t)x * FDIM + f];
            out[(size_t)x * FDIM + f] = fmaxf(v, 0.f);
        }
    }
}

extern "C" void kernel_launch(void* const* d_in, const int* in_sizes, int n_in,
                              void* d_out, int out_size, void* d_ws, size_t ws_size,
                              hipStream_t stream) {
    const float* fx_in = (const float*)d_in[0];
    const float* fp_in = (const float*)d_in[1];
    const float* Wembd = (const float*)d_in[2];
    const float* bembd = (const float*)d_in[3];
    const float* Wfc   = (const float*)d_in[4];
    const float* bfc   = (const float*)d_in[5];
    const float* Wout  = (const float*)d_in[6];
    const float* bout  = (const float*)d_in[7];

    float* out   = (float*)d_out;
    float* w_out = out + (size_t)NX * FDIM;

    ushort_t* f_b     = (ushort_t*)d_ws;                     // 6144*512
    ushort_t* We_b    = f_b + (size_t)NTOT * FDIM;           // 512*512
    ushort_t* femb_b  = We_b + (size_t)FDIM * FDIM;          // 8*6144*64
    ushort_t* fpT_b   = femb_b + (size_t)NH * NTOT * FATT;   // 8*64*4096
    ushort_t* facat_b = fpT_b + (size_t)NH * FATT * NP;      // 8*2048*128
    ushort_t* fcout_b = facat_b + (size_t)NH * NX * 128;     // 2048*512
    ushort_t* Wfc_b   = fcout_b + (size_t)NX * FDIM;         // 8*64*128
    ushort_t* Wout_b  = Wfc_b + (size_t)NH * FATT * 2 * FATT;// 512*512

    k_prep  <<<1024, 256, 0, stream>>>(fx_in, fp_in, Wembd, Wfc, Wout,
                                       f_b, We_b, Wfc_b, Wout_b);
    k_embed <<<dim3(96, 8), 256, 0, stream>>>(f_b, We_b, bembd, femb_b, fpT_b, facat_b);
    k_attn2 <<<256, 512, 0, stream>>>(femb_b, fpT_b, w_out, facat_b);
    k_fc    <<<dim3(32, 8), 256, 0, stream>>>(facat_b, Wfc_b, bfc, fcout_b);
    k_out   <<<dim3(32, 8), 256, 0, stream>>>(fx_in, fcout_b, Wout_b, bout, out);
}

// Round 17
// 191.552 us; speedup vs baseline: 2.0413x; 1.1855x over previous
//
#include <hip/hip_runtime.h>

typedef unsigned short ushort_t;
using frag_ab = __attribute__((ext_vector_type(8))) short;
using f32x4   = __attribute__((ext_vector_type(4))) float;
using u32x4   = __attribute__((ext_vector_type(4))) unsigned int;
using u32x2   = __attribute__((ext_vector_type(2))) unsigned int;

#define FDIM 512
#define NH 8
#define FATT 64
#define NX 2048
#define NP 4096
#define NTOT 6144

__device__ __forceinline__ ushort_t f2bf(float f) {
    unsigned u = __float_as_uint(f);
    u = (u + 0x7FFFu + ((u >> 16) & 1u)) >> 16;   // RTNE
    return (ushort_t)u;
}
__device__ __forceinline__ float bf2f(ushort_t s) {
    return __uint_as_float(((unsigned)s) << 16);
}
__device__ __forceinline__ unsigned pk2bf(float a, float b) {
    return (unsigned)f2bf(a) | ((unsigned)f2bf(b) << 16);
}

// ---------------------------------------------------------------------------
// K0: fp32 -> bf16 conversions: f = concat(fx, fp0), Wembd, Wfc, Wout
// ---------------------------------------------------------------------------
__global__ __launch_bounds__(256) void k_prep(const float* __restrict__ fx,
                                              const float* __restrict__ fp,
                                              const float* __restrict__ We,
                                              const float* __restrict__ Wfc,
                                              const float* __restrict__ Wout,
                                              ushort_t* __restrict__ f_b,
                                              ushort_t* __restrict__ We_b,
                                              ushort_t* __restrict__ Wfc_b,
                                              ushort_t* __restrict__ Wout_b) {
    int i = blockIdx.x * 256 + threadIdx.x;
    int stride = gridDim.x * 256;
    const int NF4 = NTOT * FDIM / 4;
    const int NX4 = NX * FDIM / 4;
    for (int idx = i; idx < NF4; idx += stride) {
        float4 v = (idx < NX4) ? ((const float4*)fx)[idx]
                               : ((const float4*)fp)[idx - NX4];
        ushort4 o;
        o.x = f2bf(v.x); o.y = f2bf(v.y); o.z = f2bf(v.z); o.w = f2bf(v.w);
        ((ushort4*)f_b)[idx] = o;
    }
    const int NW4 = FDIM * FDIM / 4;
    for (int idx = i; idx < NW4; idx += stride) {
        float4 v = ((const float4*)We)[idx];
        ushort4 o;
        o.x = f2bf(v.x); o.y = f2bf(v.y); o.z = f2bf(v.z); o.w = f2bf(v.w);
        ((ushort4*)We_b)[idx] = o;
    }
    const int NFC4 = NH * FATT * 2 * FATT / 4;
    for (int idx = i; idx < NFC4; idx += stride) {
        float4 v = ((const float4*)Wfc)[idx];
        ushort4 o;
        o.x = f2bf(v.x); o.y = f2bf(v.y); o.z = f2bf(v.z); o.w = f2bf(v.w);
        ((ushort4*)Wfc_b)[idx] = o;
    }
    for (int idx = i; idx < NW4; idx += stride) {
        float4 v = ((const float4*)Wout)[idx];
        ushort4 o;
        o.x = f2bf(v.x); o.y = f2bf(v.y); o.z = f2bf(v.z); o.w = f2bf(v.w);
        ((ushort4*)Wout_b)[idx] = o;
    }
}

// ---------------------------------------------------------------------------
// K1: femb[h][n][e] = f[n] . Wembd[h][e] + bembd  (MFMA GEMM, bf16 out)
//     also writes fpT[h][e][p] (n>=NX) and facat[h][x][64+e] (n<NX)
// ---------------------------------------------------------------------------
__global__ __launch_bounds__(256) void k_embed(const ushort_t* __restrict__ f_b,
                                               const ushort_t* __restrict__ We_b,
                                               const float* __restrict__ bembd,
                                               ushort_t* __restrict__ femb_b,
                                               ushort_t* __restrict__ fpT_b,
                                               ushort_t* __restrict__ facat_b) {
    int tid = threadIdx.x;
    int wv = tid >> 6, lane = tid & 63;
    int g = lane >> 4, c = lane & 15;
    int m0 = blockIdx.x * 64 + wv * 16;
    int o0 = blockIdx.y * 64;

    f32x4 acc[4] = {};
    const ushort_t* arow = f_b + (size_t)(m0 + c) * FDIM + g * 8;
#pragma unroll 4
    for (int ks = 0; ks < FDIM; ks += 32) {
        frag_ab a = *(const frag_ab*)(arow + ks);
#pragma unroll
        for (int t = 0; t < 4; ++t) {
            const ushort_t* brow = We_b + (size_t)(o0 + t * 16 + c) * FDIM + ks + g * 8;
            frag_ab b = *(const frag_ab*)brow;
            acc[t] = __builtin_amdgcn_mfma_f32_16x16x32_bf16(a, b, acc[t], 0, 0, 0);
        }
    }
#pragma unroll
    for (int t = 0; t < 4; ++t) {
        int o = o0 + t * 16 + c;           // output feature = h*64+e
        int h = o >> 6, e = o & 63;
        float bia = bembd[o];
#pragma unroll
        for (int r = 0; r < 4; ++r) {
            int n = m0 + g * 4 + r;
            ushort_t v = f2bf(acc[t][r] + bia);
            femb_b[((size_t)h * NTOT + n) * FATT + e] = v;
            if (n >= NX) fpT_b[((size_t)h * FATT + e) * NP + (n - NX)] = v;
            else         facat_b[((size_t)h * NX + n) * 128 + 64 + e] = v;
        }
    }
}

// ---------------------------------------------------------------------------
// K2a: attention pass-1 ONLY (round-16 k_attn2 minus pass-2). 256 blocks
//   (1/CU), 64 x-rows per block, K/V reads amortized over 64 x. Writes
//   facat bf16 + inv_sums.
// ---------------------------------------------------------------------------
__global__ __launch_bounds__(512) void k_attn_p1(const ushort_t* __restrict__ femb_b,
                                                 const ushort_t* __restrict__ fpT_b,
                                                 float* __restrict__ inv_sums,
                                                 ushort_t* __restrict__ facat_b) {
    int bid = blockIdx.x;
    int h  = bid & 7;                 // head == XCD affinity
    int xb = bid >> 3;                // 0..31, x-base = xb*64
    int tid = threadIdx.x;
    int wv = tid >> 6;                // 0..7 -> 512-p slice
    int lane = tid & 63;
    int g = lane >> 4, c = lane & 15;

    __shared__ float lds_pv[64][68];  // combined PV [x_local][e], pad 68
    __shared__ float lds_sum[64];
    __shared__ float lds_inv[64];

    const ushort_t* fxb = femb_b + (size_t)h * NTOT * FATT;
    const ushort_t* fpb = fxb + (size_t)NX * FATT;
    const ushort_t* fTb = fpT_b + (size_t)h * FATT * NP;

    // Q B-frags for 4 x-groups
    frag_ab bx0_0, bx0_1, bx1_0, bx1_1, bx2_0, bx2_1, bx3_0, bx3_1;
    {
        const ushort_t* b0 = fxb + (size_t)(xb * 64 + 0 * 16 + c) * FATT + g * 8;
        const ushort_t* b1 = fxb + (size_t)(xb * 64 + 1 * 16 + c) * FATT + g * 8;
        const ushort_t* b2 = fxb + (size_t)(xb * 64 + 2 * 16 + c) * FATT + g * 8;
        const ushort_t* b3 = fxb + (size_t)(xb * 64 + 3 * 16 + c) * FATT + g * 8;
        bx0_0 = *(const frag_ab*)b0;  bx0_1 = *(const frag_ab*)(b0 + 32);
        bx1_0 = *(const frag_ab*)b1;  bx1_1 = *(const frag_ab*)(b1 + 32);
        bx2_0 = *(const frag_ab*)b2;  bx2_1 = *(const frag_ab*)(b2 + 32);
        bx3_0 = *(const frag_ab*)b3;  bx3_1 = *(const frag_ab*)(b3 + 32);
    }

    f32x4 pacc[4][4] = {};            // [xg][t2], static indices only
    float rsum[4] = {0.f, 0.f, 0.f, 0.f};
    const int p0 = wv * 512;

    for (int ps = p0; ps < p0 + 512; ps += 16) {
        const ushort_t* ar = fpb + (size_t)(ps + c) * FATT + g * 8;
        frag_ab a0 = *(const frag_ab*)ar;
        frag_ab a1 = *(const frag_ab*)(ar + 32);
        frag_ab pb[4];
#pragma unroll
        for (int xg = 0; xg < 4; ++xg) {
            frag_ab q0 = (xg == 0) ? bx0_0 : (xg == 1) ? bx1_0 : (xg == 2) ? bx2_0 : bx3_0;
            frag_ab q1 = (xg == 0) ? bx0_1 : (xg == 1) ? bx1_1 : (xg == 2) ? bx2_1 : bx3_1;
            f32x4 s = {};
            s = __builtin_amdgcn_mfma_f32_16x16x32_bf16(a0, q0, s, 0, 0, 0);
            s = __builtin_amdgcn_mfma_f32_16x16x32_bf16(a1, q1, s, 0, 0, 0);
            float e0 = __expf(s[0] * 0.125f);
            float e1 = __expf(s[1] * 0.125f);
            float e2 = __expf(s[2] * 0.125f);
            float e3 = __expf(s[3] * 0.125f);
            rsum[xg] += (e0 + e1) + (e2 + e3);
            u32x4 bw;
            bw[0] = pk2bf(e0, e1);
            bw[1] = pk2bf(e2, e3);
            bw[2] = 0u;
            bw[3] = 0u;
            pb[xg] = __builtin_bit_cast(frag_ab, bw);
        }
#pragma unroll
        for (int t2 = 0; t2 < 4; ++t2) {
            const ushort_t* vr = fTb + (size_t)(t2 * 16 + c) * NP + ps + g * 4;
            u32x2 vl = *(const u32x2*)vr;
            u32x4 aw;
            aw[0] = vl[0];
            aw[1] = vl[1];
            aw[2] = 0u;
            aw[3] = 0u;
            frag_ab va = __builtin_bit_cast(frag_ab, aw);
#pragma unroll
            for (int xg = 0; xg < 4; ++xg)
                pacc[xg][t2] = __builtin_amdgcn_mfma_f32_16x16x32_bf16(va, pb[xg], pacc[xg][t2], 0, 0, 0);
        }
    }

#pragma unroll
    for (int xg = 0; xg < 4; ++xg) {
        rsum[xg] += __shfl_xor(rsum[xg], 16);
        rsum[xg] += __shfl_xor(rsum[xg], 32);
    }

    // cross-wave combine: 8 serialized accumulation rounds
    for (int w = 0; w < 8; ++w) {
        if (wv == w) {
            if (w == 0) {
                if (lane < 16) {
#pragma unroll
                    for (int xg = 0; xg < 4; ++xg) lds_sum[xg * 16 + c] = rsum[xg];
                }
#pragma unroll
                for (int xg = 0; xg < 4; ++xg)
#pragma unroll
                    for (int t2 = 0; t2 < 4; ++t2)
                        *(f32x4*)&lds_pv[xg * 16 + c][t2 * 16 + 4 * g] = pacc[xg][t2];
            } else {
                if (lane < 16) {
#pragma unroll
                    for (int xg = 0; xg < 4; ++xg) lds_sum[xg * 16 + c] += rsum[xg];
                }
#pragma unroll
                for (int xg = 0; xg < 4; ++xg)
#pragma unroll
                    for (int t2 = 0; t2 < 4; ++t2) {
                        f32x4 cur = *(const f32x4*)&lds_pv[xg * 16 + c][t2 * 16 + 4 * g];
                        cur += pacc[xg][t2];
                        *(f32x4*)&lds_pv[xg * 16 + c][t2 * 16 + 4 * g] = cur;
                    }
            }
        }
        __syncthreads();
    }
    if (tid < 64) {
        float inv = 1.f / lds_sum[tid];
        lds_inv[tid] = inv;
        inv_sums[(size_t)h * NX + xb * 64 + tid] = inv;
    }
    __syncthreads();

    // facat write: 512 threads x 8 elems = 64 x-rows x 64 e
    {
        int row = tid >> 3;
        int e0 = (tid & 7) * 8;
        float inv = lds_inv[row];
        u32x4 o;
#pragma unroll
        for (int j = 0; j < 4; ++j)
            o[j] = pk2bf(lds_pv[row][e0 + 2 * j] * inv, lds_pv[row][e0 + 2 * j + 1] * inv);
        *(u32x4*)&facat_b[((size_t)h * NX + xb * 64 + row) * 128 + e0] = o;
    }
}

// ---------------------------------------------------------------------------
// K2b: w_out writer (round-9 validated) — swapped MFMA + LDS transpose:
//   every global store is a 512B contiguous run (64 lanes x float2), REGULAR
//   (cached) stores. 4 waves/block, wave owns (xt, 512-p slice); h = bid%8.
// ---------------------------------------------------------------------------
__global__ __launch_bounds__(256) void k_wout(const ushort_t* __restrict__ femb_b,
                                              const float* __restrict__ inv_sums,
                                              float* __restrict__ w_out) {
    int bid = blockIdx.x;
    int h  = bid & 7;
    int wv = threadIdx.x >> 6;
    int t1 = (bid >> 3) * 4 + wv;      // 0..1023
    int xt = t1 & 127;
    int sl = t1 >> 7;                  // 0..7 (512-p slices)
    int lane = threadIdx.x & 63;
    int g = lane >> 4, c = lane & 15;

    __shared__ float lds[4][16][132];  // per-wave 16 x-rows x 128 p (pad 4)

    const ushort_t* fxb = femb_b + (size_t)h * NTOT * FATT;
    const ushort_t* fpb = fxb + (size_t)NX * FATT;

    // B = fx cols (x = xt*16 + c)
    const ushort_t* brow = fxb + (size_t)(xt * 16 + c) * FATT + g * 8;
    frag_ab b0 = *(const frag_ab*)(brow);
    frag_ab b1 = *(const frag_ab*)(brow + 32);
    float inv_c = inv_sums[(size_t)h * NX + xt * 16 + c];   // for x = c

    const int p0 = sl * 512;
    for (int chunk = 0; chunk < 512; chunk += 128) {
#pragma unroll
        for (int pt = 0; pt < 8; ++pt) {       // 16-p tiles within chunk
            int ps = p0 + chunk + pt * 16;
            const ushort_t* arow = fpb + (size_t)(ps + c) * FATT + g * 8;
            f32x4 s = {};
            s = __builtin_amdgcn_mfma_f32_16x16x32_bf16(*(const frag_ab*)arow, b0, s, 0, 0, 0);
            s = __builtin_amdgcn_mfma_f32_16x16x32_bf16(*(const frag_ab*)(arow + 32), b1, s, 0, 0, 0);
            // lane holds w for p = ps + 4g + r (r=0..3), x = c
            f32x4 ev;
            ev[0] = __expf(s[0] * 0.125f) * inv_c;
            ev[1] = __expf(s[1] * 0.125f) * inv_c;
            ev[2] = __expf(s[2] * 0.125f) * inv_c;
            ev[3] = __expf(s[3] * 0.125f) * inv_c;
            int sw = (pt * 16 + g * 4) ^ ((c & 7) << 4);   // XOR swizzle (16-f32 gran)
            *(f32x4*)&lds[wv][c][sw] = ev;
        }
        __syncthreads();   // all waves same trip count; orders LDS writes->reads
        // contiguous row writes: 64 lanes x float2 = 512B per instruction
#pragma unroll
        for (int row = 0; row < 16; ++row) {
            int pi = lane * 2;
            int swr = pi ^ ((row & 7) << 4);
            float2 v = *(const float2*)&lds[wv][row][swr];
            float* dst = w_out + ((size_t)(xt * 16 + row) * NH + h) * NP + p0 + chunk + pi;
            *(float2*)dst = v;
        }
        __syncthreads();   // WAR before next chunk overwrites the tile
    }
}

// ---------------------------------------------------------------------------
// K3: fc — per-head MFMA GEMM (2048 x 64out x 128k), relu, bf16 out
// ---------------------------------------------------------------------------
__global__ __launch_bounds__(256) void k_fc(const ushort_t* __restrict__ facat_b,
                                            const ushort_t* __restrict__ Wfc_b,
                                            const float* __restrict__ bfc,
                                            ushort_t* __restrict__ fcout_b) {
    int tid = threadIdx.x;
    int wv = tid >> 6, lane = tid & 63;
    int g = lane >> 4, c = lane & 15;
    int x0 = blockIdx.x * 64 + wv * 16;
    int h = blockIdx.y;

    const ushort_t* A = facat_b + ((size_t)h * NX + x0 + c) * 128 + g * 8;
    const ushort_t* B = Wfc_b + (size_t)h * FATT * 128;

    f32x4 acc[4] = {};
#pragma unroll
    for (int ks = 0; ks < 128; ks += 32) {
        frag_ab a = *(const frag_ab*)(A + ks);
#pragma unroll
        for (int t = 0; t < 4; ++t) {
            frag_ab b = *(const frag_ab*)(B + (size_t)(t * 16 + c) * 128 + ks + g * 8);
            acc[t] = __builtin_amdgcn_mfma_f32_16x16x32_bf16(a, b, acc[t], 0, 0, 0);
        }
    }
#pragma unroll
    for (int t = 0; t < 4; ++t) {
        int e = t * 16 + c;
        float bia = bfc[h * FATT + e];
#pragma unroll
        for (int r = 0; r < 4; ++r) {
            int x = x0 + g * 4 + r;
            fcout_b[(size_t)x * FDIM + h * FATT + e] = f2bf(fmaxf(acc[t][r] + bia, 0.f));
        }
    }
}

// ---------------------------------------------------------------------------
// K4: out GEMM (2048 x 512 x 512) MFMA + residual + bias + relu (fp32 out)
// ---------------------------------------------------------------------------
__global__ __launch_bounds__(256) void k_out(const float* __restrict__ fx_in,
                                             const ushort_t* __restrict__ fcout_b,
                                             const ushort_t* __restrict__ Wout_b,
                                             const float* __restrict__ bout,
                                             float* __restrict__ out) {
    int tid = threadIdx.x;
    int wv = tid >> 6, lane = tid & 63;
    int g = lane >> 4, c = lane & 15;
    int x0 = blockIdx.x * 64 + wv * 16;
    int o0 = blockIdx.y * 64;

    f32x4 acc[4] = {};
    const ushort_t* A = fcout_b + (size_t)(x0 + c) * FDIM + g * 8;
#pragma unroll 4
    for (int ks = 0; ks < FDIM; ks += 32) {
        frag_ab a = *(const frag_ab*)(A + ks);
#pragma unroll
        for (int t = 0; t < 4; ++t) {
            frag_ab b = *(const frag_ab*)(Wout_b + (size_t)(o0 + t * 16 + c) * FDIM + ks + g * 8);
            acc[t] = __builtin_amdgcn_mfma_f32_16x16x32_bf16(a, b, acc[t], 0, 0, 0);
        }
    }
#pragma unroll
    for (int t = 0; t < 4; ++t) {
        int f = o0 + t * 16 + c;
        float bia = bout[f];
#pragma unroll
        for (int r = 0; r < 4; ++r) {
            int x = x0 + g * 4 + r;
            float v = acc[t][r] + bia + fx_in[(size_t)x * FDIM + f];
            out[(size_t)x * FDIM + f] = fmaxf(v, 0.f);
        }
    }
}

extern "C" void kernel_launch(void* const* d_in, const int* in_sizes, int n_in,
                              void* d_out, int out_size, void* d_ws, size_t ws_size,
                              hipStream_t stream) {
    const float* fx_in = (const float*)d_in[0];
    const float* fp_in = (const float*)d_in[1];
    const float* Wembd = (const float*)d_in[2];
    const float* bembd = (const float*)d_in[3];
    const float* Wfc   = (const float*)d_in[4];
    const float* bfc   = (const float*)d_in[5];
    const float* Wout  = (const float*)d_in[6];
    const float* bout  = (const float*)d_in[7];

    float* out   = (float*)d_out;
    float* w_out = out + (size_t)NX * FDIM;

    ushort_t* f_b     = (ushort_t*)d_ws;                     // 6144*512
    ushort_t* We_b    = f_b + (size_t)NTOT * FDIM;           // 512*512
    ushort_t* femb_b  = We_b + (size_t)FDIM * FDIM;          // 8*6144*64
    ushort_t* fpT_b   = femb_b + (size_t)NH * NTOT * FATT;   // 8*64*4096
    ushort_t* facat_b = fpT_b + (size_t)NH * FATT * NP;      // 8*2048*128
    ushort_t* fcout_b = facat_b + (size_t)NH * NX * 128;     // 2048*512
    ushort_t* Wfc_b   = fcout_b + (size_t)NX * FDIM;         // 8*64*128
    ushort_t* Wout_b  = Wfc_b + (size_t)NH * FATT * 2 * FATT;// 512*512
    float*    inv_sums= (float*)(Wout_b + (size_t)FDIM * FDIM); // 8*2048 f32

    k_prep   <<<1024, 256, 0, stream>>>(fx_in, fp_in, Wembd, Wfc, Wout,
                                        f_b, We_b, Wfc_b, Wout_b);
    k_embed  <<<dim3(96, 8), 256, 0, stream>>>(f_b, We_b, bembd, femb_b, fpT_b, facat_b);
    k_attn_p1<<<256, 512, 0, stream>>>(femb_b, fpT_b, inv_sums, facat_b);
    k_wout   <<<2048, 256, 0, stream>>>(femb_b, inv_sums, w_out);
    k_fc     <<<dim3(32, 8), 256, 0, stream>>>(facat_b, Wfc_b, bfc, fcout_b);
    k_out    <<<dim3(32, 8), 256, 0, stream>>>(fx_in, fcout_b, Wout_b, bout, out);
}